// Round 1
// baseline (336.716 us; speedup 1.0000x reference)
//
#include <hip/hip_runtime.h>

#define NB 65536
#define D 64
#define NRK 3
#define SLOPE 0.2f

__device__ __forceinline__ float wave_reduce_sum(float v) {
#pragma unroll
    for (int off = 32; off >= 1; off >>= 1)
        v += __shfl_xor(v, off, 64);
    return v;
}

__device__ __forceinline__ int lower_bound(const int* __restrict__ seg, int n, int key) {
    int lo = 0, hi = n;
    while (lo < hi) {
        int mid = (lo + hi) >> 1;
        if (seg[mid] < key) lo = mid + 1;
        else hi = mid;
    }
    return lo;
}

__global__ __launch_bounds__(256)
void aspect_kernel(const int* __restrict__ user_id,
                   const int* __restrict__ a_ids, const int* __restrict__ a_seg, int Ta,
                   const int* __restrict__ c_ids, const int* __restrict__ c_seg, int Tc,
                   const float* __restrict__ user_factors,
                   const float* __restrict__ entity_factors,
                   const float* __restrict__ relation_k,
                   float* __restrict__ out)
{
    const int wave = (blockIdx.x * blockDim.x + threadIdx.x) >> 6;
    const int lane = threadIdx.x & 63;
    if (wave >= NB) return;
    const int b = wave;

    const int uid = user_id[b];
    const float u = user_factors[uid * D + lane];

    // ---- scores = softmax(leaky_relu(u @ relation_k)) over 3 ----
    float l0 = wave_reduce_sum(u * relation_k[lane * NRK + 0]);
    float l1 = wave_reduce_sum(u * relation_k[lane * NRK + 1]);
    float l2 = wave_reduce_sum(u * relation_k[lane * NRK + 2]);
    l0 = l0 > 0.f ? l0 : SLOPE * l0;
    l1 = l1 > 0.f ? l1 : SLOPE * l1;
    l2 = l2 > 0.f ? l2 : SLOPE * l2;
    const float m  = fmaxf(l0, fmaxf(l1, l2));
    const float e0 = __expf(l0 - m);
    const float e1 = __expf(l1 - m);
    const float e2 = __expf(l2 - m);
    const float inv = 1.0f / (e0 + e1 + e2);
    const float s0 = e0 * inv, s1 = e1 * inv, s2 = e2 * inv;

    // ---- artists contribution ----
    const int sa = lower_bound(a_seg, Ta, b);
    const int ea = lower_bound(a_seg, Ta, b + 1);
    float acc0 = 0.f, acc1 = 0.f;
    {
        int t = sa;
        for (; t + 4 <= ea; t += 4) {
            const int i0 = a_ids[t + 0];
            const int i1 = a_ids[t + 1];
            const int i2 = a_ids[t + 2];
            const int i3 = a_ids[t + 3];
            acc0 += entity_factors[i0 * D + lane] + entity_factors[i1 * D + lane];
            acc1 += entity_factors[i2 * D + lane] + entity_factors[i3 * D + lane];
        }
        for (; t < ea; ++t)
            acc0 += entity_factors[a_ids[t] * D + lane];
    }
    const float c_a = wave_reduce_sum((acc0 + acc1) * u) / (float)(ea - sa);

    // ---- categories contribution ----
    const int sc = lower_bound(c_seg, Tc, b);
    const int ec = lower_bound(c_seg, Tc, b + 1);
    acc0 = 0.f; acc1 = 0.f;
    {
        int t = sc;
        for (; t + 4 <= ec; t += 4) {
            const int i0 = c_ids[t + 0];
            const int i1 = c_ids[t + 1];
            const int i2 = c_ids[t + 2];
            const int i3 = c_ids[t + 3];
            acc0 += entity_factors[i0 * D + lane] + entity_factors[i1 * D + lane];
            acc1 += entity_factors[i2 * D + lane] + entity_factors[i3 * D + lane];
        }
        for (; t < ec; ++t)
            acc0 += entity_factors[c_ids[t] * D + lane];
    }
    const float c_c = wave_reduce_sum((acc0 + acc1) * u) / (float)(ec - sc);

    const float pred = (c_a * s0 + c_c * s1) / (s0 + s1);

    if (lane == 0) {
        out[b]          = pred;
        out[4 * NB + b] = c_a;
        out[5 * NB + b] = c_c;
    }
    if (lane < 3) {
        const float sv = (lane == 0) ? s0 : ((lane == 1) ? s1 : s2);
        out[NB + 3 * b + lane] = sv;
    }
}

extern "C" void kernel_launch(void* const* d_in, const int* in_sizes, int n_in,
                              void* d_out, int out_size, void* d_ws, size_t ws_size,
                              hipStream_t stream) {
    const int*   user_id        = (const int*)d_in[0];
    const int*   artists_ids    = (const int*)d_in[1];
    const int*   artists_seg    = (const int*)d_in[2];
    const int*   categories_ids = (const int*)d_in[3];
    const int*   categories_seg = (const int*)d_in[4];
    const float* user_factors   = (const float*)d_in[5];
    const float* entity_factors = (const float*)d_in[6];
    const float* relation_k     = (const float*)d_in[7];
    float* out = (float*)d_out;

    const int Ta = in_sizes[1];
    const int Tc = in_sizes[3];

    // one wave per row, 4 waves per block
    const int blocks = NB / 4;
    aspect_kernel<<<blocks, 256, 0, stream>>>(user_id,
                                              artists_ids, artists_seg, Ta,
                                              categories_ids, categories_seg, Tc,
                                              user_factors, entity_factors, relation_k,
                                              out);
}

// Round 2
// 121.505 us; speedup vs baseline: 2.7712x; 2.7712x over previous
//
#include <hip/hip_runtime.h>

#define NB 65536
#define D 64
#define SLOPE 0.2f

// reduce over the 16 lanes of a chunk-group (lanes differing in low 4 bits)
__device__ __forceinline__ float reduce16(float v) {
#pragma unroll
    for (int off = 1; off <= 8; off <<= 1)
        v += __shfl_xor(v, off, 64);
    return v;
}
// full 64-lane reduce
__device__ __forceinline__ float reduce64(float v) {
#pragma unroll
    for (int off = 1; off <= 32; off <<= 1)
        v += __shfl_xor(v, off, 64);
    return v;
}

__device__ __forceinline__ int lower_bound(const int* __restrict__ seg, int n, int key) {
    int lo = 0, hi = n;
    while (lo < hi) {
        int mid = (lo + hi) >> 1;
        if (seg[mid] < key) lo = mid + 1;
        else hi = mid;
    }
    return lo;
}

// boundary-detect pass: offs[b] = first t with seg[t]==b; offs[B] = T
__global__ __launch_bounds__(256)
void build_offsets(const int* __restrict__ seg, int T, int* __restrict__ offs) {
    int t = blockIdx.x * blockDim.x + threadIdx.x;
    if (t >= T) return;
    int s = seg[t];
    if (t == 0) offs[0] = 0;
    else if (seg[t - 1] != s) offs[s] = t;
    if (t == T - 1) offs[s + 1] = T;
}

template<bool USE_OFFS>
__global__ __launch_bounds__(256)
void aspect_kernel(const int* __restrict__ user_id,
                   const int* __restrict__ a_ids, const int* __restrict__ a_seg,
                   const int* __restrict__ offs_a, int Ta,
                   const int* __restrict__ c_ids, const int* __restrict__ c_seg,
                   const int* __restrict__ offs_c, int Tc,
                   const float* __restrict__ user_factors,
                   const float4* __restrict__ ef4,
                   const float* __restrict__ relation_k,
                   float* __restrict__ out)
{
    const int wave = (blockIdx.x * blockDim.x + threadIdx.x) >> 6;
    const int lane = threadIdx.x & 63;
    const int g = lane >> 4;   // row group 0..3
    const int k = lane & 15;   // float4 chunk 0..15
    const int b = wave;

    const int uid = user_id[b];
    const float4 u4 = reinterpret_cast<const float4*>(user_factors)[uid * 16 + k];

    // ---- logits: dot(u, rk[:,j]) ; partial over chunk k, identical across groups ----
    float p0 = 0.f, p1 = 0.f, p2 = 0.f;
    {
        const float uv[4] = {u4.x, u4.y, u4.z, u4.w};
#pragma unroll
        for (int j = 0; j < 4; ++j) {
            const int row = 4 * k + j;
            p0 += uv[j] * relation_k[row * 3 + 0];
            p1 += uv[j] * relation_k[row * 3 + 1];
            p2 += uv[j] * relation_k[row * 3 + 2];
        }
    }
    float l0 = reduce16(p0), l1 = reduce16(p1), l2 = reduce16(p2);
    l0 = l0 > 0.f ? l0 : SLOPE * l0;
    l1 = l1 > 0.f ? l1 : SLOPE * l1;
    l2 = l2 > 0.f ? l2 : SLOPE * l2;
    const float m  = fmaxf(l0, fmaxf(l1, l2));
    const float e0 = __expf(l0 - m);
    const float e1 = __expf(l1 - m);
    const float e2 = __expf(l2 - m);
    const float inv = 1.0f / (e0 + e1 + e2);
    const float s0 = e0 * inv, s1 = e1 * inv, s2 = e2 * inv;

    int sa, ea, sc, ec;
    if (USE_OFFS) {
        sa = offs_a[b]; ea = offs_a[b + 1];
        sc = offs_c[b]; ec = offs_c[b + 1];
    } else {
        sa = lower_bound(a_seg, Ta, b); ea = lower_bound(a_seg, Ta, b + 1);
        sc = lower_bound(c_seg, Tc, b); ec = lower_bound(c_seg, Tc, b + 1);
    }

    // ---- gather-sum entity rows (4 rows per load instr, 8 in flight), dot with u ----
    auto gather_dot = [&](const int* __restrict__ ids, int s, int e) -> float {
        float ax = 0.f, ay = 0.f, az = 0.f, aw = 0.f;
        float bx = 0.f, by = 0.f, bz = 0.f, bw = 0.f;
        int t = s;
        for (; t + 8 <= e; t += 8) {
            const int i0 = ids[t + g];
            const int i1 = ids[t + 4 + g];
            const float4 v0 = ef4[i0 * 16 + k];
            const float4 v1 = ef4[i1 * 16 + k];
            ax += v0.x; ay += v0.y; az += v0.z; aw += v0.w;
            bx += v1.x; by += v1.y; bz += v1.z; bw += v1.w;
        }
        if (t + 4 <= e) {
            const int i0 = ids[t + g];
            const float4 v0 = ef4[i0 * 16 + k];
            ax += v0.x; ay += v0.y; az += v0.z; aw += v0.w;
            t += 4;
        }
        if (t + g < e) {
            const int i0 = ids[t + g];
            const float4 v0 = ef4[i0 * 16 + k];
            bx += v0.x; by += v0.y; bz += v0.z; bw += v0.w;
        }
        const float part = (ax + bx) * u4.x + (ay + by) * u4.y +
                           (az + bz) * u4.z + (aw + bw) * u4.w;
        return reduce64(part);
    };

    const float c_a = gather_dot(a_ids, sa, ea) / (float)(ea - sa);
    const float c_c = gather_dot(c_ids, sc, ec) / (float)(ec - sc);

    const float pred = (c_a * s0 + c_c * s1) / (s0 + s1);

    if (lane == 0) {
        out[b]          = pred;
        out[4 * NB + b] = c_a;
        out[5 * NB + b] = c_c;
    }
    if (lane < 3) {
        const float sv = (lane == 0) ? s0 : ((lane == 1) ? s1 : s2);
        out[NB + 3 * b + lane] = sv;
    }
}

extern "C" void kernel_launch(void* const* d_in, const int* in_sizes, int n_in,
                              void* d_out, int out_size, void* d_ws, size_t ws_size,
                              hipStream_t stream) {
    const int*   user_id        = (const int*)d_in[0];
    const int*   artists_ids    = (const int*)d_in[1];
    const int*   artists_seg    = (const int*)d_in[2];
    const int*   categories_ids = (const int*)d_in[3];
    const int*   categories_seg = (const int*)d_in[4];
    const float* user_factors   = (const float*)d_in[5];
    const float* entity_factors = (const float*)d_in[6];
    const float* relation_k     = (const float*)d_in[7];
    float* out = (float*)d_out;

    const int Ta = in_sizes[1];
    const int Tc = in_sizes[3];

    const size_t need = (size_t)2 * (NB + 1) * sizeof(int);
    const int blocks = NB / 4;  // one wave per row, 4 waves/block

    if (ws_size >= need) {
        int* offs_a = (int*)d_ws;
        int* offs_c = offs_a + (NB + 1);
        build_offsets<<<(Ta + 255) / 256, 256, 0, stream>>>(artists_seg, Ta, offs_a);
        build_offsets<<<(Tc + 255) / 256, 256, 0, stream>>>(categories_seg, Tc, offs_c);
        aspect_kernel<true><<<blocks, 256, 0, stream>>>(user_id,
            artists_ids, artists_seg, offs_a, Ta,
            categories_ids, categories_seg, offs_c, Tc,
            user_factors, (const float4*)entity_factors, relation_k, out);
    } else {
        aspect_kernel<false><<<blocks, 256, 0, stream>>>(user_id,
            artists_ids, artists_seg, nullptr, Ta,
            categories_ids, categories_seg, nullptr, Tc,
            user_factors, (const float4*)entity_factors, relation_k, out);
    }
}

// Round 3
// 112.393 us; speedup vs baseline: 2.9959x; 1.0811x over previous
//
#include <hip/hip_runtime.h>

#define NB 65536
#define D 64
#define SLOPE 0.2f

__device__ __forceinline__ float reduce16(float v) {
#pragma unroll
    for (int off = 1; off <= 8; off <<= 1)
        v += __shfl_xor(v, off, 64);
    return v;
}
__device__ __forceinline__ float reduce64(float v) {
#pragma unroll
    for (int off = 1; off <= 32; off <<= 1)
        v += __shfl_xor(v, off, 64);
    return v;
}

__device__ __forceinline__ int lower_bound(const int* __restrict__ seg, int n, int key) {
    int lo = 0, hi = n;
    while (lo < hi) {
        int mid = (lo + hi) >> 1;
        if (seg[mid] < key) lo = mid + 1;
        else hi = mid;
    }
    return lo;
}

// offs[b] = first t with seg[t]==b; offs[B] = T  (segments contiguous, all non-empty)
__global__ __launch_bounds__(256)
void build_offsets(const int* __restrict__ seg, int T, int* __restrict__ offs) {
    int t = blockIdx.x * blockDim.x + threadIdx.x;
    if (t >= T) return;
    int s = seg[t];
    if (t == 0) offs[0] = 0;
    else if (seg[t - 1] != s) offs[s] = t;
    if (t == T - 1) offs[s + 1] = T;
}

// fp32 -> packed bf16 pairs (RTN)
__device__ __forceinline__ unsigned rtn_hi(float x) {
    unsigned u = __float_as_uint(x);
    return u + 0x7FFFu + ((u >> 16) & 1u);   // keep high 16 after this
}
__global__ __launch_bounds__(256)
void convert_bf16(const float2* __restrict__ in, unsigned* __restrict__ out, int n2) {
    int i = blockIdx.x * blockDim.x + threadIdx.x;
    if (i >= n2) return;
    float2 v = in[i];
    unsigned lo = rtn_hi(v.x) >> 16;
    unsigned hi = rtn_hi(v.y) & 0xFFFF0000u;
    out[i] = hi | lo;
}

// MODE: 0 = bsearch + fp32, 1 = offsets + fp32, 2 = offsets + bf16 table
template<int MODE>
__global__ __launch_bounds__(256)
void aspect_kernel(const int* __restrict__ user_id,
                   const int* __restrict__ a_ids, const int* __restrict__ a_seg,
                   const int* __restrict__ offs_a, int Ta,
                   const int* __restrict__ c_ids, const int* __restrict__ c_seg,
                   const int* __restrict__ offs_c, int Tc,
                   const float* __restrict__ user_factors,
                   const float4* __restrict__ ef4,
                   const unsigned char* __restrict__ efb,   // bf16 table (128 B/row)
                   const float* __restrict__ relation_k,
                   float* __restrict__ out)
{
    const int wave = (blockIdx.x * blockDim.x + threadIdx.x) >> 6;
    const int lane = threadIdx.x & 63;
    const int g = lane >> 4;    // row subgroup 0..3
    const int k = lane & 15;    // dim chunk 0..15 (dims 4k..4k+3)
    const int b = wave;

    const int uid = user_id[b];
    const float4 u4 = reinterpret_cast<const float4*>(user_factors)[uid * 16 + k];

    // ---- logits + softmax (3-way) ----
    float p0 = 0.f, p1 = 0.f, p2 = 0.f;
    {
        const float uv[4] = {u4.x, u4.y, u4.z, u4.w};
#pragma unroll
        for (int j = 0; j < 4; ++j) {
            const int row = 4 * k + j;
            p0 += uv[j] * relation_k[row * 3 + 0];
            p1 += uv[j] * relation_k[row * 3 + 1];
            p2 += uv[j] * relation_k[row * 3 + 2];
        }
    }
    float l0 = reduce16(p0), l1 = reduce16(p1), l2 = reduce16(p2);
    l0 = l0 > 0.f ? l0 : SLOPE * l0;
    l1 = l1 > 0.f ? l1 : SLOPE * l1;
    l2 = l2 > 0.f ? l2 : SLOPE * l2;
    const float m  = fmaxf(l0, fmaxf(l1, l2));
    const float e0 = __expf(l0 - m);
    const float e1 = __expf(l1 - m);
    const float e2 = __expf(l2 - m);
    const float inv = 1.0f / (e0 + e1 + e2);
    const float s0 = e0 * inv, s1 = e1 * inv, s2 = e2 * inv;

    int sa, ea, sc, ec;
    if (MODE >= 1) {
        sa = offs_a[b]; ea = offs_a[b + 1];
        sc = offs_c[b]; ec = offs_c[b + 1];
    } else {
        sa = lower_bound(a_seg, Ta, b); ea = lower_bound(a_seg, Ta, b + 1);
        sc = lower_bound(c_seg, Tc, b); ec = lower_bound(c_seg, Tc, b + 1);
    }

    const unsigned k8 = (unsigned)(k << 3);

    // bf16 path: 16 rows/chunk; 1 coalesced id load + 4 shuffled gathers
    auto gather_dot_bf16 = [&](const int* __restrict__ ids, int s, int e) -> float {
        float part = 0.f;
        int t = s;
        for (; t + 16 <= e; t += 16) {
            const int idl = ids[t + k];
#pragma unroll
            for (int j = 0; j < 4; ++j) {
                const int id = __shfl(idl, 4 * j + g, 64);
                const unsigned off = ((unsigned)id << 7) + k8;
                const uint2 w = *reinterpret_cast<const uint2*>(efb + off);
                part = fmaf(__uint_as_float(w.x << 16),          u4.x, part);
                part = fmaf(__uint_as_float(w.x & 0xFFFF0000u),  u4.y, part);
                part = fmaf(__uint_as_float(w.y << 16),          u4.z, part);
                part = fmaf(__uint_as_float(w.y & 0xFFFF0000u),  u4.w, part);
            }
        }
        if (t < e) {
            const int idl = ids[min(t + k, e - 1)];
#pragma unroll
            for (int j = 0; j < 4; ++j) {
                const int row = t + 4 * j + g;
                if (row < e) {
                    const int id = __shfl(idl, 4 * j + g, 64);
                    const unsigned off = ((unsigned)id << 7) + k8;
                    const uint2 w = *reinterpret_cast<const uint2*>(efb + off);
                    part = fmaf(__uint_as_float(w.x << 16),          u4.x, part);
                    part = fmaf(__uint_as_float(w.x & 0xFFFF0000u),  u4.y, part);
                    part = fmaf(__uint_as_float(w.y << 16),          u4.z, part);
                    part = fmaf(__uint_as_float(w.y & 0xFFFF0000u),  u4.w, part);
                }
            }
        }
        return reduce64(part);
    };

    // fp32 fallback path (R2 structure)
    auto gather_dot_f32 = [&](const int* __restrict__ ids, int s, int e) -> float {
        float ax = 0.f, ay = 0.f, az = 0.f, aw = 0.f;
        float bx = 0.f, by = 0.f, bz = 0.f, bw = 0.f;
        int t = s;
        for (; t + 8 <= e; t += 8) {
            const int i0 = ids[t + g];
            const int i1 = ids[t + 4 + g];
            const float4 v0 = ef4[i0 * 16 + k];
            const float4 v1 = ef4[i1 * 16 + k];
            ax += v0.x; ay += v0.y; az += v0.z; aw += v0.w;
            bx += v1.x; by += v1.y; bz += v1.z; bw += v1.w;
        }
        if (t + 4 <= e) {
            const int i0 = ids[t + g];
            const float4 v0 = ef4[i0 * 16 + k];
            ax += v0.x; ay += v0.y; az += v0.z; aw += v0.w;
            t += 4;
        }
        if (t + g < e) {
            const int i0 = ids[t + g];
            const float4 v0 = ef4[i0 * 16 + k];
            bx += v0.x; by += v0.y; bz += v0.z; bw += v0.w;
        }
        const float part = (ax + bx) * u4.x + (ay + by) * u4.y +
                           (az + bz) * u4.z + (aw + bw) * u4.w;
        return reduce64(part);
    };

    float c_a, c_c;
    if (MODE == 2) {
        c_a = gather_dot_bf16(a_ids, sa, ea) / (float)(ea - sa);
        c_c = gather_dot_bf16(c_ids, sc, ec) / (float)(ec - sc);
    } else {
        c_a = gather_dot_f32(a_ids, sa, ea) / (float)(ea - sa);
        c_c = gather_dot_f32(c_ids, sc, ec) / (float)(ec - sc);
    }

    const float pred = (c_a * s0 + c_c * s1) / (s0 + s1);

    if (lane == 0) {
        out[b]          = pred;
        out[4 * NB + b] = c_a;
        out[5 * NB + b] = c_c;
    }
    if (lane < 3) {
        const float sv = (lane == 0) ? s0 : ((lane == 1) ? s1 : s2);
        out[NB + 3 * b + lane] = sv;
    }
}

extern "C" void kernel_launch(void* const* d_in, const int* in_sizes, int n_in,
                              void* d_out, int out_size, void* d_ws, size_t ws_size,
                              hipStream_t stream) {
    const int*   user_id        = (const int*)d_in[0];
    const int*   artists_ids    = (const int*)d_in[1];
    const int*   artists_seg    = (const int*)d_in[2];
    const int*   categories_ids = (const int*)d_in[3];
    const int*   categories_seg = (const int*)d_in[4];
    const float* user_factors   = (const float*)d_in[5];
    const float* entity_factors = (const float*)d_in[6];
    const float* relation_k     = (const float*)d_in[7];
    float* out = (float*)d_out;

    const int Ta = in_sizes[1];
    const int Tc = in_sizes[3];
    const int n_ent_elems = in_sizes[6];           // N_ENTITY * D
    const int n2 = n_ent_elems / 2;

    const size_t offs_bytes  = (size_t)2 * (NB + 1) * sizeof(int);
    const size_t table_bytes = (size_t)n_ent_elems * 2;      // bf16
    const int blocks = NB / 4;   // one wave per row, 4 waves/block

    if (ws_size >= offs_bytes + table_bytes) {
        int* offs_a = (int*)d_ws;
        int* offs_c = offs_a + (NB + 1);
        unsigned char* efb = (unsigned char*)d_ws + offs_bytes;
        build_offsets<<<(Ta + 255) / 256, 256, 0, stream>>>(artists_seg, Ta, offs_a);
        build_offsets<<<(Tc + 255) / 256, 256, 0, stream>>>(categories_seg, Tc, offs_c);
        convert_bf16<<<(n2 + 255) / 256, 256, 0, stream>>>(
            (const float2*)entity_factors, (unsigned*)efb, n2);
        aspect_kernel<2><<<blocks, 256, 0, stream>>>(user_id,
            artists_ids, artists_seg, offs_a, Ta,
            categories_ids, categories_seg, offs_c, Tc,
            user_factors, (const float4*)entity_factors, efb, relation_k, out);
    } else if (ws_size >= offs_bytes) {
        int* offs_a = (int*)d_ws;
        int* offs_c = offs_a + (NB + 1);
        build_offsets<<<(Ta + 255) / 256, 256, 0, stream>>>(artists_seg, Ta, offs_a);
        build_offsets<<<(Tc + 255) / 256, 256, 0, stream>>>(categories_seg, Tc, offs_c);
        aspect_kernel<1><<<blocks, 256, 0, stream>>>(user_id,
            artists_ids, artists_seg, offs_a, Ta,
            categories_ids, categories_seg, offs_c, Tc,
            user_factors, (const float4*)entity_factors, nullptr, relation_k, out);
    } else {
        aspect_kernel<0><<<blocks, 256, 0, stream>>>(user_id,
            artists_ids, artists_seg, nullptr, Ta,
            categories_ids, categories_seg, nullptr, Tc,
            user_factors, (const float4*)entity_factors, nullptr, relation_k, out);
    }
}

// Round 5
// 106.498 us; speedup vs baseline: 3.1617x; 1.0554x over previous
//
#include <hip/hip_runtime.h>

#define NB 65536
#define D 64
#define SLOPE 0.2f

typedef _Float16 h2f __attribute__((ext_vector_type(2)));

__device__ __forceinline__ h2f as_h2(unsigned x) {
    union { unsigned u; h2f h; } v; v.u = x; return v.h;
}

// reduce over lanes differing in bits 0..2 (the 8 dim-chunk lanes)
__device__ __forceinline__ float reduce8(float v) {
#pragma unroll
    for (int off = 1; off <= 4; off <<= 1)
        v += __shfl_xor(v, off, 64);
    return v;
}
__device__ __forceinline__ float reduce64(float v) {
#pragma unroll
    for (int off = 1; off <= 32; off <<= 1)
        v += __shfl_xor(v, off, 64);
    return v;
}

__device__ __forceinline__ int lower_bound(const int* __restrict__ seg, int n, int key) {
    int lo = 0, hi = n;
    while (lo < hi) {
        int mid = (lo + hi) >> 1;
        if (seg[mid] < key) lo = mid + 1;
        else hi = mid;
    }
    return lo;
}

// merged pre-pass: fp32 -> f16 table convert + both segment-offset builds
__global__ __launch_bounds__(256)
void prepass(const float2* __restrict__ ef2, unsigned* __restrict__ eh, int n2,
             const int* __restrict__ a_seg, int Ta, int* __restrict__ offs_a,
             const int* __restrict__ c_seg, int Tc, int* __restrict__ offs_c)
{
    const int t = blockIdx.x * blockDim.x + threadIdx.x;
    if (t < n2) {
        float2 v = ef2[t];
        h2f h = { (_Float16)v.x, (_Float16)v.y };
        union { h2f h; unsigned u; } cv; cv.h = h;
        eh[t] = cv.u;
    }
    if (t < Ta) {
        int s = a_seg[t];
        if (t == 0) offs_a[0] = 0;
        else if (a_seg[t - 1] != s) offs_a[s] = t;
        if (t == Ta - 1) offs_a[s + 1] = Ta;
    }
    if (t < Tc) {
        int s = c_seg[t];
        if (t == 0) offs_c[0] = 0;
        else if (c_seg[t - 1] != s) offs_c[s] = t;
        if (t == Tc - 1) offs_c[s + 1] = Tc;
    }
}

struct UH { h2f h0, h1, h2, h3; };

__device__ __forceinline__ float dot8(uint4 w, const UH& u, float acc) {
#if __has_builtin(__builtin_amdgcn_fdot2)
    acc = __builtin_amdgcn_fdot2(as_h2(w.x), u.h0, acc, false);
    acc = __builtin_amdgcn_fdot2(as_h2(w.y), u.h1, acc, false);
    acc = __builtin_amdgcn_fdot2(as_h2(w.z), u.h2, acc, false);
    acc = __builtin_amdgcn_fdot2(as_h2(w.w), u.h3, acc, false);
#else
    h2f t0 = as_h2(w.x) * u.h0 + as_h2(w.y) * u.h1;
    h2f t1 = as_h2(w.z) * u.h2 + as_h2(w.w) * u.h3;
    acc += (float)t0.x + (float)t0.y + (float)t1.x + (float)t1.y;
#endif
    return acc;
}

// MODE: 1 = offsets + f16 table, 0 = bsearch + fp32 fallback
template<int MODE>
__global__ __launch_bounds__(256)
void aspect_kernel(const int* __restrict__ user_id,
                   const int* __restrict__ a_ids, const int* __restrict__ a_seg,
                   const int* __restrict__ offs_a, int Ta,
                   const int* __restrict__ c_ids, const int* __restrict__ c_seg,
                   const int* __restrict__ offs_c, int Tc,
                   const float* __restrict__ user_factors,
                   const float4* __restrict__ ef4,       // fp32 fallback table
                   const uint4* __restrict__ efh,        // f16 table, 8 uint4 per row
                   const float* __restrict__ relation_k,
                   float* __restrict__ out)
{
    const int wave = (blockIdx.x * blockDim.x + threadIdx.x) >> 6;
    const int lane = threadIdx.x & 63;
    const int r = lane >> 3;    // row subgroup 0..7
    const int c = lane & 7;     // dim chunk 0..7 (dims 8c..8c+7)
    const int b = wave;

    const int uid = user_id[b];
    const float4 ua = reinterpret_cast<const float4*>(user_factors)[uid * 16 + 2 * c];
    const float4 ub = reinterpret_cast<const float4*>(user_factors)[uid * 16 + 2 * c + 1];

    // ---- logits over this lane's 8 dims, reduced over the 8 c-lanes ----
    float p0 = 0.f, p1 = 0.f, p2 = 0.f;
    {
        const float uv[8] = {ua.x, ua.y, ua.z, ua.w, ub.x, ub.y, ub.z, ub.w};
#pragma unroll
        for (int j = 0; j < 8; ++j) {
            const int row = 8 * c + j;
            p0 += uv[j] * relation_k[row * 3 + 0];
            p1 += uv[j] * relation_k[row * 3 + 1];
            p2 += uv[j] * relation_k[row * 3 + 2];
        }
    }
    float l0 = reduce8(p0), l1 = reduce8(p1), l2 = reduce8(p2);
    l0 = l0 > 0.f ? l0 : SLOPE * l0;
    l1 = l1 > 0.f ? l1 : SLOPE * l1;
    l2 = l2 > 0.f ? l2 : SLOPE * l2;
    const float m  = fmaxf(l0, fmaxf(l1, l2));
    const float e0 = __expf(l0 - m);
    const float e1 = __expf(l1 - m);
    const float e2 = __expf(l2 - m);
    const float inv = 1.0f / (e0 + e1 + e2);
    const float s0 = e0 * inv, s1 = e1 * inv, s2 = e2 * inv;

    int sa, ea, sc, ec;
    if (MODE == 1) {
        sa = offs_a[b]; ea = offs_a[b + 1];
        sc = offs_c[b]; ec = offs_c[b + 1];
    } else {
        sa = lower_bound(a_seg, Ta, b); ea = lower_bound(a_seg, Ta, b + 1);
        sc = lower_bound(c_seg, Tc, b); ec = lower_bound(c_seg, Tc, b + 1);
    }

    // lane's u as 4 half2 (for v_dot2_f32_f16)
    UH uh;
    uh.h0 = h2f{ (_Float16)ua.x, (_Float16)ua.y };
    uh.h1 = h2f{ (_Float16)ua.z, (_Float16)ua.w };
    uh.h2 = h2f{ (_Float16)ub.x, (_Float16)ub.y };
    uh.h3 = h2f{ (_Float16)ub.z, (_Float16)ub.w };

    // f16 gather: 8 rows per wave-load (16 B/lane), 16 rows in flight
    auto gather_dot_f16 = [&](const int* __restrict__ ids, int s, int e) -> float {
        float acc = 0.f;
        int t = s;
        for (; t + 16 <= e; t += 16) {
            const int id0 = ids[t + r];
            const int id1 = ids[t + 8 + r];
            const uint4 w0 = efh[id0 * 8 + c];
            const uint4 w1 = efh[id1 * 8 + c];
            acc = dot8(w0, uh, acc);
            acc = dot8(w1, uh, acc);
        }
        if (t + r < e) {
            const uint4 w0 = efh[ids[t + r] * 8 + c];
            acc = dot8(w0, uh, acc);
        }
        t += 8;
        if (t < e && t + r < e) {
            const uint4 w1 = efh[ids[t + r] * 8 + c];
            acc = dot8(w1, uh, acc);
        }
        return reduce64(acc);
    };

    // fp32 fallback (R2 structure, 4-row float4 gathers)
    auto gather_dot_f32 = [&](const int* __restrict__ ids, int s, int e) -> float {
        const int g = lane >> 4, k = lane & 15;
        const float4 u4 = reinterpret_cast<const float4*>(user_factors)[uid * 16 + k];
        float ax = 0.f, ay = 0.f, az = 0.f, aw = 0.f;
        int t = s;
        for (; t + 4 <= e; t += 4) {
            const int i0 = ids[t + g];
            const float4 v0 = ef4[i0 * 16 + k];
            ax += v0.x; ay += v0.y; az += v0.z; aw += v0.w;
        }
        if (t + g < e) {
            const int i0 = ids[t + g];
            const float4 v0 = ef4[i0 * 16 + k];
            ax += v0.x; ay += v0.y; az += v0.z; aw += v0.w;
        }
        const float part = ax * u4.x + ay * u4.y + az * u4.z + aw * u4.w;
        return reduce64(part);
    };

    float c_a, c_c;
    if (MODE == 1) {
        c_a = gather_dot_f16(a_ids, sa, ea) / (float)(ea - sa);
        c_c = gather_dot_f16(c_ids, sc, ec) / (float)(ec - sc);
    } else {
        c_a = gather_dot_f32(a_ids, sa, ea) / (float)(ea - sa);
        c_c = gather_dot_f32(c_ids, sc, ec) / (float)(ec - sc);
    }

    const float pred = (c_a * s0 + c_c * s1) / (s0 + s1);

    if (lane == 0) {
        out[b]          = pred;
        out[4 * NB + b] = c_a;
        out[5 * NB + b] = c_c;
    }
    if (lane < 3) {
        const float sv = (lane == 0) ? s0 : ((lane == 1) ? s1 : s2);
        out[NB + 3 * b + lane] = sv;
    }
}

extern "C" void kernel_launch(void* const* d_in, const int* in_sizes, int n_in,
                              void* d_out, int out_size, void* d_ws, size_t ws_size,
                              hipStream_t stream) {
    const int*   user_id        = (const int*)d_in[0];
    const int*   artists_ids    = (const int*)d_in[1];
    const int*   artists_seg    = (const int*)d_in[2];
    const int*   categories_ids = (const int*)d_in[3];
    const int*   categories_seg = (const int*)d_in[4];
    const float* user_factors   = (const float*)d_in[5];
    const float* entity_factors = (const float*)d_in[6];
    const float* relation_k     = (const float*)d_in[7];
    float* out = (float*)d_out;

    const int Ta = in_sizes[1];
    const int Tc = in_sizes[3];
    const int n_ent_elems = in_sizes[6];    // N_ENTITY * D
    const int n2 = n_ent_elems / 2;

    const size_t offs_bytes  = (size_t)2 * (NB + 1) * sizeof(int);
    const size_t table_bytes = (size_t)n_ent_elems * 2;   // f16
    const int blocks = NB / 4;   // one wave per row, 4 waves/block

    if (ws_size >= offs_bytes + table_bytes) {
        int* offs_a = (int*)d_ws;
        int* offs_c = offs_a + (NB + 1);
        unsigned* efh = (unsigned*)((unsigned char*)d_ws + offs_bytes);
        int prep_n = n2 > Ta ? n2 : Ta;
        if (Tc > prep_n) prep_n = Tc;
        prepass<<<(prep_n + 255) / 256, 256, 0, stream>>>(
            (const float2*)entity_factors, efh, n2,
            artists_seg, Ta, offs_a,
            categories_seg, Tc, offs_c);
        aspect_kernel<1><<<blocks, 256, 0, stream>>>(user_id,
            artists_ids, artists_seg, offs_a, Ta,
            categories_ids, categories_seg, offs_c, Tc,
            user_factors, (const float4*)entity_factors, (const uint4*)efh,
            relation_k, out);
    } else {
        aspect_kernel<0><<<blocks, 256, 0, stream>>>(user_id,
            artists_ids, artists_seg, nullptr, Ta,
            categories_ids, categories_seg, nullptr, Tc,
            user_factors, (const float4*)entity_factors, nullptr,
            relation_k, out);
    }
}